// Round 4
// baseline (632.743 us; speedup 1.0000x reference)
//
#include <hip/hip_runtime.h>
#include <hip/hip_bf16.h>
#include <math.h>

typedef __bf16 bf16x8 __attribute__((ext_vector_type(8)));
typedef float f32x4 __attribute__((ext_vector_type(4)));
typedef short short4v __attribute__((ext_vector_type(4)));

typedef __attribute__((address_space(3))) unsigned int lds_u32_t;
typedef __attribute__((address_space(1))) const unsigned int glb_u32_t;

static __device__ __forceinline__ f32x4 mfma16(bf16x8 a, bf16x8 b, f32x4 c) {
  return __builtin_amdgcn_mfma_f32_16x16x32_bf16(a, b, c, 0, 0, 0);
}

// K=16 PV mfma: native 16x16x16 bf16 if available, else zero-padded 16x16x32
// (A upper-K half = 0 kills the garbage B upper half -> identical result).
static __device__ __forceinline__ f32x4 pv_mfma(short4v p, short4v v, f32x4 c) {
#if __has_builtin(__builtin_amdgcn_mfma_f32_16x16x16bf16_1k)
  return __builtin_amdgcn_mfma_f32_16x16x16bf16_1k(p, v, c, 0, 0, 0);
#else
  union { short s[8]; bf16x8 v8; } a, b;
  a.s[0] = p.x; a.s[1] = p.y; a.s[2] = p.z; a.s[3] = p.w;
  a.s[4] = a.s[5] = a.s[6] = a.s[7] = 0;
  b.s[0] = v.x; b.s[1] = v.y; b.s[2] = v.z; b.s[3] = v.w;
  b.s[4] = b.s[5] = b.s[6] = b.s[7] = 0;
  return __builtin_amdgcn_mfma_f32_16x16x32_bf16(a.v8, b.v8, c, 0, 0, 0);
#endif
}

static __device__ __forceinline__ void load_lds16(const __bf16* g, __bf16* l) {
  __builtin_amdgcn_global_load_lds((glb_u32_t*)g, (lds_u32_t*)l, 16, 0, 0);
}

// ---------------- weight transpose: src[R][C] fp32 -> dst[C][R] bf16 ----------------
__global__ __launch_bounds__(256) void transpose_w(const float* __restrict__ src,
                                                   __bf16* __restrict__ dst,
                                                   int R, int C) {
  __shared__ float tile[32][33];
  int tx = threadIdx.x, ty = threadIdx.y;
  int c0 = blockIdx.x * 32, r0 = blockIdx.y * 32;
#pragma unroll
  for (int i = 0; i < 4; i++)
    tile[ty + 8 * i][tx] = src[(size_t)(r0 + ty + 8 * i) * C + c0 + tx];
  __syncthreads();
#pragma unroll
  for (int i = 0; i < 4; i++)
    dst[(size_t)(c0 + ty + 8 * i) * R + r0 + tx] = (__bf16)tile[tx][ty + 8 * i];
}

// ---------------- layernorm (row=1024) fp32 in -> bf16 out ----------------
__global__ __launch_bounds__(256) void ln_kernel(const float* __restrict__ x,
                                                 const float* __restrict__ w,
                                                 const float* __restrict__ b,
                                                 __bf16* __restrict__ out) {
  int row = blockIdx.x, tid = threadIdx.x;
  const float* xr = x + (size_t)row * 1024;
  float v[4];
  float s = 0.f, sq = 0.f;
#pragma unroll
  for (int i = 0; i < 4; i++) {
    v[i] = xr[tid + 256 * i];
    s += v[i];
    sq += v[i] * v[i];
  }
#pragma unroll
  for (int off = 1; off < 64; off <<= 1) {
    s += __shfl_xor(s, off, 64);
    sq += __shfl_xor(sq, off, 64);
  }
  __shared__ float red[8];
  int wave = tid >> 6, lane = tid & 63;
  if (lane == 0) { red[wave] = s; red[4 + wave] = sq; }
  __syncthreads();
  if (tid == 0) {
    float S = red[0] + red[1] + red[2] + red[3];
    float SQ = red[4] + red[5] + red[6] + red[7];
    float mu = S * (1.f / 1024.f);
    float var = SQ * (1.f / 1024.f) - mu * mu;
    red[0] = mu;
    red[1] = rsqrtf(var + 1e-5f);
  }
  __syncthreads();
  float mu = red[0], rstd = red[1];
  __bf16* orow = out + (size_t)row * 1024;
#pragma unroll
  for (int i = 0; i < 4; i++) {
    int c = tid + 256 * i;
    orow[c] = (__bf16)((v[i] - mu) * rstd * w[c] + b[c]);
  }
}

// ---------------- GEMM: A[M][K] bf16 x Bt[N][K] bf16, templated epilogue ----------------
enum { MODE_QKV = 0, MODE_WO = 3, MODE_F1 = 4, MODE_F2 = 5 };

template <int MODE>
__global__ __launch_bounds__(256, 2) void gemm_bt(const __bf16* __restrict__ A,
                                                  const __bf16* __restrict__ Bt,
                                                  const float* __restrict__ b0,
                                                  const float* __restrict__ b1,
                                                  const float* __restrict__ b2,
                                                  const float* __restrict__ aux,
                                                  void* __restrict__ o0,
                                                  void* __restrict__ o1,
                                                  void* __restrict__ o2,
                                                  int N, int K) {
  __shared__ __align__(16) __bf16 As[128 * 64];
  __shared__ __align__(16) __bf16 Bs[128 * 64];
  const int tid = threadIdx.x;
  const int m0 = blockIdx.y * 128, n0 = blockIdx.x * 128;
  const int wave = tid >> 6, lane = tid & 63, quad = lane >> 4, l16 = lane & 15;
  const int wm = (wave >> 1) * 64, wn = (wave & 1) * 64;

  int srow[4], sgran[4];
#pragma unroll
  for (int i = 0; i < 4; i++) {
    int inst = wave * 4 + i;
    srow[i] = inst * 8 + (lane >> 3);
    sgran[i] = (lane & 7) ^ (srow[i] & 7);
  }

  const f32x4 zero4 = {0.f, 0.f, 0.f, 0.f};
  f32x4 acc[4][4];
#pragma unroll
  for (int i = 0; i < 4; i++)
#pragma unroll
    for (int j = 0; j < 4; j++) acc[i][j] = zero4;

  for (int kt = 0; kt < K; kt += 64) {
#pragma unroll
    for (int i = 0; i < 4; i++) {
      int inst = wave * 4 + i;
      load_lds16(&A[(size_t)(m0 + srow[i]) * K + kt + sgran[i] * 8], &As[inst * 512]);
      load_lds16(&Bt[(size_t)(n0 + srow[i]) * K + kt + sgran[i] * 8], &Bs[inst * 512]);
    }
    __syncthreads();
#pragma unroll
    for (int ks = 0; ks < 64; ks += 32) {
      bf16x8 af[4], bfv[4];
#pragma unroll
      for (int mi = 0; mi < 4; mi++) {
        int row = wm + 16 * mi + l16;
        int pg = ((ks >> 3) + quad) ^ (row & 7);
        af[mi] = *(const bf16x8*)&As[row * 64 + pg * 8];
      }
#pragma unroll
      for (int ni = 0; ni < 4; ni++) {
        int row = wn + 16 * ni + l16;
        int pg = ((ks >> 3) + quad) ^ (row & 7);
        bfv[ni] = *(const bf16x8*)&Bs[row * 64 + pg * 8];
      }
#pragma unroll
      for (int mi = 0; mi < 4; mi++)
#pragma unroll
        for (int ni = 0; ni < 4; ni++)
          acc[mi][ni] = mfma16(af[mi], bfv[ni], acc[mi][ni]);
    }
    __syncthreads();
  }

  int seg = (n0 >> 10);
  const float* bsel = (MODE == MODE_QKV) ? (seg == 0 ? b0 : seg == 1 ? b1 : b2) : b0;

#pragma unroll
  for (int mi = 0; mi < 4; mi++) {
#pragma unroll
    for (int ni = 0; ni < 4; ni++) {
      int ncol = n0 + wn + 16 * ni + l16;
      int cc = ncol & 1023;
      float bval = bsel[(MODE == MODE_QKV) ? cc : ncol];
#pragma unroll
      for (int r = 0; r < 4; r++) {
        int m = m0 + wm + 16 * mi + quad * 4 + r;
        float val = acc[mi][ni][r] + bval;
        if constexpr (MODE == MODE_QKV) {
          int bb = m >> 10, s = m & 1023, h = cc >> 6, dk = cc & 63;
          if (seg == 0)
            ((__bf16*)o0)[(((size_t)(bb * 16 + h)) * 1024 + s) * 64 + dk] =
                (__bf16)(val * 0.125f);
          else if (seg == 1)
            ((__bf16*)o1)[(((size_t)(bb * 16 + h)) * 1024 + s) * 64 + dk] = (__bf16)val;
          else
            ((__bf16*)o2)[(((size_t)(bb * 16 + h)) * 64 + dk) * 1024 + s] = (__bf16)val;
        } else if constexpr (MODE == MODE_WO) {
          val = fmaxf(val, 0.f);
          size_t idx = (size_t)m * 1024 + ncol;
          ((float*)o0)[idx] = aux[idx] + val;
        } else if constexpr (MODE == MODE_F1) {
          float g = 0.5f * val * (1.f + erff(val * 0.70710678118654752f));
          ((__bf16*)o0)[(size_t)m * 4096 + ncol] = (__bf16)g;
        } else {  // MODE_F2
          size_t idx = (size_t)m * 1024 + ncol;
          ((float*)o0)[idx] = aux[idx] + val;
        }
      }
    }
  }
}

// ---------------- flash attention v4: all-register, zero LDS, zero barriers ----------------
// Computes S^T = K·Q^T so the MFMA C-layout of exp(S^T) IS the A-operand layout
// of a K=16 PV mfma: lane holds P[q=l16][key=ni*16+4*quad+r]. No LDS round trip.
// K register-double-buffered; V (8B frags from Vt rows) issued before the S MFMAs.
// Denominator: one scalar/lane (q=l16), reduced across quads once at the end.
__global__ __launch_bounds__(256) void attn_kernel(const __bf16* __restrict__ Q,
                                                   const __bf16* __restrict__ Kp,
                                                   const __bf16* __restrict__ Vt,
                                                   __bf16* __restrict__ ctx) {
  const int tid = threadIdx.x;
  const int bh = blockIdx.x, qb = blockIdx.y;
  const int wave = tid >> 6, lane = tid & 63, quad = lane >> 4, l16 = lane & 15;
  const int qrow0 = qb * 128 + wave * 32;

  // Q as B-operand of S^T: B^T[n=q][k=dk] -> same 16B row loads as before
  bf16x8 aq[2][2];
#pragma unroll
  for (int mi = 0; mi < 2; mi++) {
    const __bf16* qrow = Q + ((size_t)bh * 1024 + qrow0 + mi * 16 + l16) * 64;
    aq[mi][0] = *(const bf16x8*)&qrow[8 * quad];
    aq[mi][1] = *(const bf16x8*)&qrow[32 + 8 * quad];
  }

  const f32x4 zero4 = {0.f, 0.f, 0.f, 0.f};
  f32x4 o[2][4];  // [q-block][dk-block]; C-layout: col=l16=dk, row=4*quad+r=q
  float lp[2] = {0.f, 0.f};
#pragma unroll
  for (int mi = 0; mi < 2; mi++)
#pragma unroll
    for (int nj = 0; nj < 4; nj++) o[mi][nj] = zero4;

  const __bf16* kb0 = Kp + (size_t)bh * 65536;
  const __bf16* vb0 = Vt + (size_t)bh * 65536;

  bf16x8 kfA[4][2], kfB[4][2];
#pragma unroll
  for (int ni = 0; ni < 4; ni++) {
    const __bf16* krow = kb0 + (16 * ni + l16) * 64;
    kfA[ni][0] = *(const bf16x8*)&krow[8 * quad];
    kfA[ni][1] = *(const bf16x8*)&krow[32 + 8 * quad];
  }

  auto body = [&](int kbk, bf16x8 (&kcur)[4][2], bf16x8 (&knxt)[4][2]) {
    // V frags for this iteration: B[k=key][n=dk] = Vt[dk][key], 4 contiguous keys
    short4v vf[4][4];  // [ni key-block][nj dk-block]
#pragma unroll
    for (int ni = 0; ni < 4; ni++)
#pragma unroll
      for (int nj = 0; nj < 4; nj++)
        vf[ni][nj] = *(const short4v*)(vb0 + (size_t)(nj * 16 + l16) * 1024 +
                                       kbk * 64 + ni * 16 + 4 * quad);
    // K prefetch for next iteration
    if (kbk < 15) {
      const __bf16* kbase = kb0 + (kbk + 1) * 4096;
#pragma unroll
      for (int ni = 0; ni < 4; ni++) {
        const __bf16* krow = kbase + (16 * ni + l16) * 64;
        knxt[ni][0] = *(const bf16x8*)&krow[8 * quad];
        knxt[ni][1] = *(const bf16x8*)&krow[32 + 8 * quad];
      }
    }
    // S^T = K Q^T : A=K-frag (m=key), B=Q-frag (n=q); waits only on kcur
    f32x4 st[2][4];
#pragma unroll
    for (int mi = 0; mi < 2; mi++)
#pragma unroll
      for (int ni = 0; ni < 4; ni++) {
        st[mi][ni] = mfma16(kcur[ni][0], aq[mi][0], zero4);
        st[mi][ni] = mfma16(kcur[ni][1], aq[mi][1], st[mi][ni]);
      }
    // exp -> P directly in PV A-operand layout (registers only)
    union { short4v s4; __bf16 b[4]; } pf[2][4];
#pragma unroll
    for (int mi = 0; mi < 2; mi++)
#pragma unroll
      for (int ni = 0; ni < 4; ni++)
#pragma unroll
        for (int r = 0; r < 4; r++) {
          float p = __expf(st[mi][ni][r]);
          lp[mi] += p;
          pf[mi][ni].b[r] = (__bf16)p;
        }
    // O += P V  (K=16 mfma per key-block)
#pragma unroll
    for (int ni = 0; ni < 4; ni++)
#pragma unroll
      for (int mi = 0; mi < 2; mi++)
#pragma unroll
        for (int nj = 0; nj < 4; nj++)
          o[mi][nj] = pv_mfma(pf[mi][ni].s4, vf[ni][nj], o[mi][nj]);
  };

  for (int kbk2 = 0; kbk2 < 16; kbk2 += 2) {
    body(kbk2, kfA, kfB);
    body(kbk2 + 1, kfB, kfA);
  }

  // lp[mi]: lane holds partial sum for q = mi*16 + l16; reduce across quads
#pragma unroll
  for (int mi = 0; mi < 2; mi++) {
    lp[mi] += __shfl_xor(lp[mi], 16, 64);
    lp[mi] += __shfl_xor(lp[mi], 32, 64);
  }

  int bb = bh >> 4, h = bh & 15;
#pragma unroll
  for (int mi = 0; mi < 2; mi++)
#pragma unroll
    for (int r = 0; r < 4; r++) {
      // this lane's O rows are q = 4*quad + r; fetch matching denominator
      float inv = 1.f / __shfl(lp[mi], 4 * quad + r, 64);
      int s = qrow0 + mi * 16 + 4 * quad + r;
#pragma unroll
      for (int nj = 0; nj < 4; nj++)
        ctx[((size_t)(bb * 1024 + s)) * 1024 + h * 64 + nj * 16 + l16] =
            (__bf16)(o[mi][nj][r] * inv);
    }
}

// ---------------- launch ----------------
extern "C" void kernel_launch(void* const* d_in, const int* in_sizes, int n_in,
                              void* d_out, int out_size, void* d_ws, size_t ws_size,
                              hipStream_t stream) {
  const float* x = (const float*)d_in[0];
  const float* ln1w = (const float*)d_in[1];
  const float* ln1b = (const float*)d_in[2];
  const float* wq = (const float*)d_in[3];
  const float* bq = (const float*)d_in[4];
  const float* wk = (const float*)d_in[5];
  const float* bk = (const float*)d_in[6];
  const float* wv = (const float*)d_in[7];
  const float* bv = (const float*)d_in[8];
  const float* wo = (const float*)d_in[9];
  const float* bo = (const float*)d_in[10];
  const float* ln2w = (const float*)d_in[11];
  const float* ln2b = (const float*)d_in[12];
  const float* w1 = (const float*)d_in[13];
  const float* b1 = (const float*)d_in[14];
  const float* w2 = (const float*)d_in[15];
  const float* b2 = (const float*)d_in[16];
  float* out = (float*)d_out;

  char* ws = (char*)d_ws;
  const size_t MB = 1024 * 1024;
  __bf16* wqkv_t = (__bf16*)(ws + 0 * MB);   // wq_t | wk_t | wv_t contiguous [3072][1024]
  __bf16* wq_t = (__bf16*)(ws + 0 * MB);
  __bf16* wk_t = (__bf16*)(ws + 2 * MB);
  __bf16* wv_t = (__bf16*)(ws + 4 * MB);
  __bf16* wo_t = (__bf16*)(ws + 6 * MB);
  __bf16* w1_t = (__bf16*)(ws + 8 * MB);
  __bf16* w2_t = (__bf16*)(ws + 16 * MB);
  __bf16* hbuf = (__bf16*)(ws + 24 * MB);    // h (LN1), later h2 (LN2)
  __bf16* qbuf = (__bf16*)(ws + 40 * MB);
  __bf16* kbuf = (__bf16*)(ws + 56 * MB);
  __bf16* vtbuf = (__bf16*)(ws + 72 * MB);
  __bf16* ctxbuf = (__bf16*)(ws + 88 * MB);
  __bf16* ff1 = (__bf16*)(ws + 40 * MB);     // aliases q/k/vt (dead by then)

  dim3 tb(32, 8);
  transpose_w<<<dim3(32, 32), tb, 0, stream>>>(wq, wq_t, 1024, 1024);
  transpose_w<<<dim3(32, 32), tb, 0, stream>>>(wk, wk_t, 1024, 1024);
  transpose_w<<<dim3(32, 32), tb, 0, stream>>>(wv, wv_t, 1024, 1024);
  transpose_w<<<dim3(32, 32), tb, 0, stream>>>(wo, wo_t, 1024, 1024);
  transpose_w<<<dim3(128, 32), tb, 0, stream>>>(w1, w1_t, 1024, 4096);
  transpose_w<<<dim3(32, 128), tb, 0, stream>>>(w2, w2_t, 4096, 1024);

  ln_kernel<<<8192, 256, 0, stream>>>(x, ln1w, ln1b, hbuf);

  gemm_bt<MODE_QKV><<<dim3(24, 64), 256, 0, stream>>>(
      hbuf, wqkv_t, bq, bk, bv, nullptr, qbuf, kbuf, vtbuf, 3072, 1024);

  attn_kernel<<<dim3(128, 8), 256, 0, stream>>>(qbuf, kbuf, vtbuf, ctxbuf);

  gemm_bt<MODE_WO><<<dim3(8, 64), 256, 0, stream>>>(
      ctxbuf, wo_t, bo, nullptr, nullptr, x, out, nullptr, nullptr, 1024, 1024);

  ln_kernel<<<8192, 256, 0, stream>>>(out, ln2w, ln2b, hbuf);

  gemm_bt<MODE_F1><<<dim3(32, 64), 256, 0, stream>>>(
      hbuf, w1_t, b1, nullptr, nullptr, nullptr, ff1, nullptr, nullptr, 4096, 1024);
  gemm_bt<MODE_F2><<<dim3(8, 64), 256, 0, stream>>>(
      ff1, w2_t, b2, nullptr, nullptr, out, out, nullptr, nullptr, 1024, 4096);
}

// Round 5
// 549.415 us; speedup vs baseline: 1.1517x; 1.1517x over previous
//
#include <hip/hip_runtime.h>
#include <hip/hip_bf16.h>
#include <math.h>

typedef __bf16 bf16x8 __attribute__((ext_vector_type(8)));
typedef __bf16 bf16x4 __attribute__((ext_vector_type(4)));
typedef float f32x4 __attribute__((ext_vector_type(4)));

typedef __attribute__((address_space(3))) unsigned int lds_u32_t;
typedef __attribute__((address_space(1))) const unsigned int glb_u32_t;

static __device__ __forceinline__ f32x4 mfma16(bf16x8 a, bf16x8 b, f32x4 c) {
  return __builtin_amdgcn_mfma_f32_16x16x32_bf16(a, b, c, 0, 0, 0);
}

static __device__ __forceinline__ float fast_exp2(float x) {
#if __has_builtin(__builtin_amdgcn_exp2f)
  return __builtin_amdgcn_exp2f(x);
#else
  return exp2f(x);
#endif
}

static __device__ __forceinline__ void load_lds16(const __bf16* g, __bf16* l) {
  __builtin_amdgcn_global_load_lds((glb_u32_t*)g, (lds_u32_t*)l, 16, 0, 0);
}

// ---------------- weight transpose: src[R][C] fp32 -> dst[C][R] bf16 ----------------
__global__ __launch_bounds__(256) void transpose_w(const float* __restrict__ src,
                                                   __bf16* __restrict__ dst,
                                                   int R, int C) {
  __shared__ float tile[32][33];
  int tx = threadIdx.x, ty = threadIdx.y;
  int c0 = blockIdx.x * 32, r0 = blockIdx.y * 32;
#pragma unroll
  for (int i = 0; i < 4; i++)
    tile[ty + 8 * i][tx] = src[(size_t)(r0 + ty + 8 * i) * C + c0 + tx];
  __syncthreads();
#pragma unroll
  for (int i = 0; i < 4; i++)
    dst[(size_t)(c0 + ty + 8 * i) * R + r0 + tx] = (__bf16)tile[tx][ty + 8 * i];
}

// ---------------- layernorm (row=1024) fp32 in -> bf16 out ----------------
__global__ __launch_bounds__(256) void ln_kernel(const float* __restrict__ x,
                                                 const float* __restrict__ w,
                                                 const float* __restrict__ b,
                                                 __bf16* __restrict__ out) {
  int row = blockIdx.x, tid = threadIdx.x;
  const float* xr = x + (size_t)row * 1024;
  float v[4];
  float s = 0.f, sq = 0.f;
#pragma unroll
  for (int i = 0; i < 4; i++) {
    v[i] = xr[tid + 256 * i];
    s += v[i];
    sq += v[i] * v[i];
  }
#pragma unroll
  for (int off = 1; off < 64; off <<= 1) {
    s += __shfl_xor(s, off, 64);
    sq += __shfl_xor(sq, off, 64);
  }
  __shared__ float red[8];
  int wave = tid >> 6, lane = tid & 63;
  if (lane == 0) { red[wave] = s; red[4 + wave] = sq; }
  __syncthreads();
  if (tid == 0) {
    float S = red[0] + red[1] + red[2] + red[3];
    float SQ = red[4] + red[5] + red[6] + red[7];
    float mu = S * (1.f / 1024.f);
    float var = SQ * (1.f / 1024.f) - mu * mu;
    red[0] = mu;
    red[1] = rsqrtf(var + 1e-5f);
  }
  __syncthreads();
  float mu = red[0], rstd = red[1];
  __bf16* orow = out + (size_t)row * 1024;
#pragma unroll
  for (int i = 0; i < 4; i++) {
    int c = tid + 256 * i;
    orow[c] = (__bf16)((v[i] - mu) * rstd * w[c] + b[c]);
  }
}

// ---------------- GEMM: A[M][K] bf16 x Bt[N][K] bf16, templated epilogue ----------------
enum { MODE_QKV = 0, MODE_WO = 3, MODE_F1 = 4, MODE_F2 = 5 };

template <int MODE>
__global__ __launch_bounds__(256, 2) void gemm_bt(const __bf16* __restrict__ A,
                                                  const __bf16* __restrict__ Bt,
                                                  const float* __restrict__ b0,
                                                  const float* __restrict__ b1,
                                                  const float* __restrict__ b2,
                                                  const float* __restrict__ aux,
                                                  void* __restrict__ o0,
                                                  void* __restrict__ o1,
                                                  void* __restrict__ o2,
                                                  int N, int K) {
  __shared__ __align__(16) __bf16 As[128 * 64];
  __shared__ __align__(16) __bf16 Bs[128 * 64];
  const int tid = threadIdx.x;
  const int m0 = blockIdx.y * 128, n0 = blockIdx.x * 128;
  const int wave = tid >> 6, lane = tid & 63, quad = lane >> 4, l16 = lane & 15;
  const int wm = (wave >> 1) * 64, wn = (wave & 1) * 64;

  int srow[4], sgran[4];
#pragma unroll
  for (int i = 0; i < 4; i++) {
    int inst = wave * 4 + i;
    srow[i] = inst * 8 + (lane >> 3);
    sgran[i] = (lane & 7) ^ (srow[i] & 7);
  }

  const f32x4 zero4 = {0.f, 0.f, 0.f, 0.f};
  f32x4 acc[4][4];
#pragma unroll
  for (int i = 0; i < 4; i++)
#pragma unroll
    for (int j = 0; j < 4; j++) acc[i][j] = zero4;

  for (int kt = 0; kt < K; kt += 64) {
#pragma unroll
    for (int i = 0; i < 4; i++) {
      int inst = wave * 4 + i;
      load_lds16(&A[(size_t)(m0 + srow[i]) * K + kt + sgran[i] * 8], &As[inst * 512]);
      load_lds16(&Bt[(size_t)(n0 + srow[i]) * K + kt + sgran[i] * 8], &Bs[inst * 512]);
    }
    __syncthreads();
#pragma unroll
    for (int ks = 0; ks < 64; ks += 32) {
      bf16x8 af[4], bfv[4];
#pragma unroll
      for (int mi = 0; mi < 4; mi++) {
        int row = wm + 16 * mi + l16;
        int pg = ((ks >> 3) + quad) ^ (row & 7);
        af[mi] = *(const bf16x8*)&As[row * 64 + pg * 8];
      }
#pragma unroll
      for (int ni = 0; ni < 4; ni++) {
        int row = wn + 16 * ni + l16;
        int pg = ((ks >> 3) + quad) ^ (row & 7);
        bfv[ni] = *(const bf16x8*)&Bs[row * 64 + pg * 8];
      }
#pragma unroll
      for (int mi = 0; mi < 4; mi++)
#pragma unroll
        for (int ni = 0; ni < 4; ni++)
          acc[mi][ni] = mfma16(af[mi], bfv[ni], acc[mi][ni]);
    }
    __syncthreads();
  }

  int seg = (n0 >> 10);
  const float* bsel = (MODE == MODE_QKV) ? (seg == 0 ? b0 : seg == 1 ? b1 : b2) : b0;

#pragma unroll
  for (int mi = 0; mi < 4; mi++) {
#pragma unroll
    for (int ni = 0; ni < 4; ni++) {
      int ncol = n0 + wn + 16 * ni + l16;
      int cc = ncol & 1023;
      float bval = bsel[(MODE == MODE_QKV) ? cc : ncol];
#pragma unroll
      for (int r = 0; r < 4; r++) {
        int m = m0 + wm + 16 * mi + quad * 4 + r;
        float val = acc[mi][ni][r] + bval;
        if constexpr (MODE == MODE_QKV) {
          int bb = m >> 10, s = m & 1023, h = cc >> 6, dk = cc & 63;
          if (seg == 0)  // fold 1/sqrt(64) * log2(e) so attn uses raw exp2
            ((__bf16*)o0)[(((size_t)(bb * 16 + h)) * 1024 + s) * 64 + dk] =
                (__bf16)(val * 0.18033688011112042f);
          else if (seg == 1)
            ((__bf16*)o1)[(((size_t)(bb * 16 + h)) * 1024 + s) * 64 + dk] = (__bf16)val;
          else
            ((__bf16*)o2)[(((size_t)(bb * 16 + h)) * 64 + dk) * 1024 + s] = (__bf16)val;
        } else if constexpr (MODE == MODE_WO) {
          val = fmaxf(val, 0.f);
          size_t idx = (size_t)m * 1024 + ncol;
          ((float*)o0)[idx] = aux[idx] + val;
        } else if constexpr (MODE == MODE_F1) {
          float g = 0.5f * val * (1.f + erff(val * 0.70710678118654752f));
          ((__bf16*)o0)[(size_t)m * 4096 + ncol] = (__bf16)g;
        } else {  // MODE_F2
          size_t idx = (size_t)m * 1024 + ncol;
          ((float*)o0)[idx] = aux[idx] + val;
        }
      }
    }
  }
}

// ---------------- flash attention v5: S^T trick + vectorized LDS round trip ----------
// S^T = K·Q^T puts P[q=l16][key=16ni+4quad+r] in each lane: 4 CONSECUTIVE keys
// per group -> P->LDS is 8 ds_write_b64 (round 3 needed 32 ds_write_b16), and
// the read-back at Ps[q][8*quad] is the exact K=32 A-operand layout -> PV stays
// 16 full-width MFMAs (round 4's K=16 path cost 1.5x MFMA cycles). Ps is
// double-buffered to break the WAR between iter i's reads and i+1's writes.
// K double-buffered in regs; V (16B frags) issued before the S MFMAs.
// Scores arrive pre-scaled by log2(e) -> bare v_exp_f32. No barriers anywhere.
__global__ __launch_bounds__(256) void attn_kernel(const __bf16* __restrict__ Q,
                                                   const __bf16* __restrict__ Kp,
                                                   const __bf16* __restrict__ Vt,
                                                   __bf16* __restrict__ ctx) {
  __shared__ __align__(16) __bf16 Ps[2][4][32][72];  // [buf][wave][q][key(+pad)]
  const int tid = threadIdx.x;
  const int bh = blockIdx.x, qb = blockIdx.y;
  const int wave = tid >> 6, lane = tid & 63, quad = lane >> 4, l16 = lane & 15;
  const int qrow0 = qb * 128 + wave * 32;

  // Q as B-operand of S^T: lane l16 = q, k = dk
  bf16x8 aq[2][2];
#pragma unroll
  for (int mi = 0; mi < 2; mi++) {
    const __bf16* qrow = Q + ((size_t)bh * 1024 + qrow0 + mi * 16 + l16) * 64;
    aq[mi][0] = *(const bf16x8*)&qrow[8 * quad];
    aq[mi][1] = *(const bf16x8*)&qrow[32 + 8 * quad];
  }

  const f32x4 zero4 = {0.f, 0.f, 0.f, 0.f};
  f32x4 o[2][4];  // [q-block][dk-block]; C: col=l16=dk, row=4quad+r=q
  float lp[2] = {0.f, 0.f};
#pragma unroll
  for (int mi = 0; mi < 2; mi++)
#pragma unroll
    for (int nj = 0; nj < 4; nj++) o[mi][nj] = zero4;

  const __bf16* kb0 = Kp + (size_t)bh * 65536;
  const __bf16* vb0 = Vt + (size_t)bh * 65536;

  bf16x8 kfA[4][2], kfB[4][2];
#pragma unroll
  for (int ni = 0; ni < 4; ni++) {
    const __bf16* krow = kb0 + (16 * ni + l16) * 64;
    kfA[ni][0] = *(const bf16x8*)&krow[8 * quad];
    kfA[ni][1] = *(const bf16x8*)&krow[32 + 8 * quad];
  }

  auto body = [&](int kbk, int buf, bf16x8 (&kcur)[4][2], bf16x8 (&knxt)[4][2]) {
    // V frags for this iteration: B^T[n=dk][k=key] = Vt rows, 16B contiguous
    bf16x8 vf[2][4];  // [key-half][dk-block]
#pragma unroll
    for (int half = 0; half < 2; half++)
#pragma unroll
      for (int nj = 0; nj < 4; nj++)
        vf[half][nj] = *(const bf16x8*)(vb0 + (size_t)(nj * 16 + l16) * 1024 +
                                        kbk * 64 + 32 * half + 8 * quad);
    // K prefetch for next iteration
    if (kbk < 15) {
      const __bf16* kbase = kb0 + (kbk + 1) * 4096;
#pragma unroll
      for (int ni = 0; ni < 4; ni++) {
        const __bf16* krow = kbase + (16 * ni + l16) * 64;
        knxt[ni][0] = *(const bf16x8*)&krow[8 * quad];
        knxt[ni][1] = *(const bf16x8*)&krow[32 + 8 * quad];
      }
    }
    // S^T = K Q^T (A = K frag, B = Q frag); waits only on kcur
    f32x4 st[2][4];
#pragma unroll
    for (int mi = 0; mi < 2; mi++)
#pragma unroll
      for (int ni = 0; ni < 4; ni++) {
        st[mi][ni] = mfma16(kcur[ni][0], aq[mi][0], zero4);
        st[mi][ni] = mfma16(kcur[ni][1], aq[mi][1], st[mi][ni]);
      }
    // exp2 (log2e pre-folded), pack 4 consecutive keys -> one ds_write_b64
#pragma unroll
    for (int mi = 0; mi < 2; mi++)
#pragma unroll
      for (int ni = 0; ni < 4; ni++) {
        union { bf16x4 v4; __bf16 b[4]; } pk;
#pragma unroll
        for (int r = 0; r < 4; r++) {
          float p = fast_exp2(st[mi][ni][r]);
          lp[mi] += p;
          pk.b[r] = (__bf16)p;
        }
        *(bf16x4*)&Ps[buf][wave][16 * mi + l16][16 * ni + 4 * quad] = pk.v4;
      }
    // read back as K=32 A-operand: A[m=q=l16][k=8*quad+j]
    bf16x8 pa[2][2];
#pragma unroll
    for (int mi = 0; mi < 2; mi++) {
      pa[mi][0] = *(const bf16x8*)&Ps[buf][wave][16 * mi + l16][8 * quad];
      pa[mi][1] = *(const bf16x8*)&Ps[buf][wave][16 * mi + l16][32 + 8 * quad];
    }
    // O += P V : 16 K=32 MFMAs
#pragma unroll
    for (int mi = 0; mi < 2; mi++)
#pragma unroll
      for (int nj = 0; nj < 4; nj++) {
        o[mi][nj] = mfma16(pa[mi][0], vf[0][nj], o[mi][nj]);
        o[mi][nj] = mfma16(pa[mi][1], vf[1][nj], o[mi][nj]);
      }
  };

  for (int kbk2 = 0; kbk2 < 16; kbk2 += 2) {
    body(kbk2, 0, kfA, kfB);
    body(kbk2 + 1, 1, kfB, kfA);
  }

  // lane holds lp for q = mi*16 + l16 (partial over its quad's keys); reduce quads
#pragma unroll
  for (int mi = 0; mi < 2; mi++) {
    lp[mi] += __shfl_xor(lp[mi], 16, 64);
    lp[mi] += __shfl_xor(lp[mi], 32, 64);
  }

  int bb = bh >> 4, h = bh & 15;
#pragma unroll
  for (int mi = 0; mi < 2; mi++)
#pragma unroll
    for (int r = 0; r < 4; r++) {
      // this lane's O rows are q = 4*quad + r; grab that q's denominator
      float inv = 1.f / __shfl(lp[mi], 4 * quad + r, 64);
      int s = qrow0 + mi * 16 + 4 * quad + r;
#pragma unroll
      for (int nj = 0; nj < 4; nj++)
        ctx[((size_t)(bb * 1024 + s)) * 1024 + h * 64 + nj * 16 + l16] =
            (__bf16)(o[mi][nj][r] * inv);
    }
}

// ---------------- launch ----------------
extern "C" void kernel_launch(void* const* d_in, const int* in_sizes, int n_in,
                              void* d_out, int out_size, void* d_ws, size_t ws_size,
                              hipStream_t stream) {
  const float* x = (const float*)d_in[0];
  const float* ln1w = (const float*)d_in[1];
  const float* ln1b = (const float*)d_in[2];
  const float* wq = (const float*)d_in[3];
  const float* bq = (const float*)d_in[4];
  const float* wk = (const float*)d_in[5];
  const float* bk = (const float*)d_in[6];
  const float* wv = (const float*)d_in[7];
  const float* bv = (const float*)d_in[8];
  const float* wo = (const float*)d_in[9];
  const float* bo = (const float*)d_in[10];
  const float* ln2w = (const float*)d_in[11];
  const float* ln2b = (const float*)d_in[12];
  const float* w1 = (const float*)d_in[13];
  const float* b1 = (const float*)d_in[14];
  const float* w2 = (const float*)d_in[15];
  const float* b2 = (const float*)d_in[16];
  float* out = (float*)d_out;

  char* ws = (char*)d_ws;
  const size_t MB = 1024 * 1024;
  __bf16* wqkv_t = (__bf16*)(ws + 0 * MB);   // wq_t | wk_t | wv_t contiguous [3072][1024]
  __bf16* wq_t = (__bf16*)(ws + 0 * MB);
  __bf16* wk_t = (__bf16*)(ws + 2 * MB);
  __bf16* wv_t = (__bf16*)(ws + 4 * MB);
  __bf16* wo_t = (__bf16*)(ws + 6 * MB);
  __bf16* w1_t = (__bf16*)(ws + 8 * MB);
  __bf16* w2_t = (__bf16*)(ws + 16 * MB);
  __bf16* hbuf = (__bf16*)(ws + 24 * MB);    // h (LN1), later h2 (LN2)
  __bf16* qbuf = (__bf16*)(ws + 40 * MB);
  __bf16* kbuf = (__bf16*)(ws + 56 * MB);
  __bf16* vtbuf = (__bf16*)(ws + 72 * MB);
  __bf16* ctxbuf = (__bf16*)(ws + 88 * MB);
  __bf16* ff1 = (__bf16*)(ws + 40 * MB);     // aliases q/k/vt (dead by then)

  dim3 tb(32, 8);
  transpose_w<<<dim3(32, 32), tb, 0, stream>>>(wq, wq_t, 1024, 1024);
  transpose_w<<<dim3(32, 32), tb, 0, stream>>>(wk, wk_t, 1024, 1024);
  transpose_w<<<dim3(32, 32), tb, 0, stream>>>(wv, wv_t, 1024, 1024);
  transpose_w<<<dim3(32, 32), tb, 0, stream>>>(wo, wo_t, 1024, 1024);
  transpose_w<<<dim3(128, 32), tb, 0, stream>>>(w1, w1_t, 1024, 4096);
  transpose_w<<<dim3(32, 128), tb, 0, stream>>>(w2, w2_t, 4096, 1024);

  ln_kernel<<<8192, 256, 0, stream>>>(x, ln1w, ln1b, hbuf);

  gemm_bt<MODE_QKV><<<dim3(24, 64), 256, 0, stream>>>(
      hbuf, wqkv_t, bq, bk, bv, nullptr, qbuf, kbuf, vtbuf, 3072, 1024);

  attn_kernel<<<dim3(128, 8), 256, 0, stream>>>(qbuf, kbuf, vtbuf, ctxbuf);

  gemm_bt<MODE_WO><<<dim3(8, 64), 256, 0, stream>>>(
      ctxbuf, wo_t, bo, nullptr, nullptr, x, out, nullptr, nullptr, 1024, 1024);

  ln_kernel<<<8192, 256, 0, stream>>>(out, ln2w, ln2b, hbuf);

  gemm_bt<MODE_F1><<<dim3(32, 64), 256, 0, stream>>>(
      hbuf, w1_t, b1, nullptr, nullptr, nullptr, ff1, nullptr, nullptr, 4096, 1024);
  gemm_bt<MODE_F2><<<dim3(8, 64), 256, 0, stream>>>(
      ff1, w2_t, b2, nullptr, nullptr, out, out, nullptr, nullptr, 1024, 4096);
}